// Round 13
// baseline (401.257 us; speedup 1.0000x reference)
//
#include <hip/hip_runtime.h>
#include <hip/hip_fp16.h>

#define NB 8
#define CC 256
#define NN 2304
#define TK 32
#define QSZ ((size_t)NB * NN * CC)

typedef __attribute__((ext_vector_type(8))) _Float16 half8;
typedef __attribute__((ext_vector_type(4))) float f32x4;
typedef __attribute__((ext_vector_type(4))) unsigned short us4;

#define MFMAH(a, b, c) __builtin_amdgcn_mfma_f32_16x16x32_f16((a), (b), (c), 0, 0, 0)

__device__ __forceinline__ unsigned short f2h(float f) {
    union { _Float16 x; unsigned short u; } c;
    c.x = (_Float16)f;
    return c.u;
}
__device__ __forceinline__ unsigned short f2bf(float f) {
    unsigned int u = __float_as_uint(f);
    u = (u + 0x7fffu + ((u >> 16) & 1u)) >> 16;
    return (unsigned short)u;
}
__device__ __forceinline__ float bf2f(unsigned short h) {
    return __uint_as_float(((unsigned int)h) << 16);
}

// ---- fold output projection + BN into per-channel scale/bias ----
__global__ void prep_s2(const float* __restrict__ w_o, const float* __restrict__ b_o,
                        const float* __restrict__ gam, const float* __restrict__ bet,
                        const float* __restrict__ mea, const float* __restrict__ var,
                        float* __restrict__ s2b2) {
    int c = threadIdx.x;
    float inv = gam[c] * rsqrtf(var[c] + 1e-5f);
    s2b2[c]      = w_o[c] * inv;
    s2b2[CC + c] = b_o[c] * inv + bet[c] - mea[c] * inv;
}

// ---- V^T projection: vt[b][c][m] = fp16(x * w_g + b_g) ----
__global__ __launch_bounds__(256) void prep_v(const float* __restrict__ x,
                                              const float* __restrict__ w_g,
                                              const float* __restrict__ b_g,
                                              unsigned short* __restrict__ vt) {
    size_t i = ((size_t)blockIdx.x * 256 + threadIdx.x) * 8;
    int c = (int)((i / NN) % CC);
    float wg = w_g[c], bg = b_g[c];
    float4 a = *(const float4*)&x[i];
    float4 d = *(const float4*)&x[i + 4];
    us4 o0, o1;
    o0[0] = f2h(a.x * wg + bg); o0[1] = f2h(a.y * wg + bg);
    o0[2] = f2h(a.z * wg + bg); o0[3] = f2h(a.w * wg + bg);
    o1[0] = f2h(d.x * wg + bg); o1[1] = f2h(d.y * wg + bg);
    o1[2] = f2h(d.z * wg + bg); o1[3] = f2h(d.w * wg + bg);
    *(us4*)&vt[i]     = o0;
    *(us4*)&vt[i + 4] = o1;
}

// ---- transpose + project x -> Q, K fp16, layout (B, N, C) ----
__global__ __launch_bounds__(256) void prep_qk(
    const float* __restrict__ x,
    const float* __restrict__ w_t, const float* __restrict__ b_t,
    const float* __restrict__ w_p, const float* __restrict__ b_p,
    unsigned short* __restrict__ qf, unsigned short* __restrict__ kf) {
    __shared__ float tile[64][65];
    int bid = blockIdx.x;
    int b  = bid / 144;
    int r  = bid % 144;
    int n0 = (r / 4) * 64;
    int c0 = (r % 4) * 64;
    int t  = threadIdx.x;
    int tx = t & 15, ty = t >> 4;

#pragma unroll
    for (int i = 0; i < 4; ++i) {
        int c = ty + i * 16;
        const float4 v = *(const float4*)&x[(size_t)(b * CC + c0 + c) * NN + n0 + tx * 4];
        tile[c][tx * 4 + 0] = v.x;
        tile[c][tx * 4 + 1] = v.y;
        tile[c][tx * 4 + 2] = v.z;
        tile[c][tx * 4 + 3] = v.w;
    }
    __syncthreads();
#pragma unroll
    for (int i = 0; i < 4; ++i) {
        int n = ty + i * 16;
        us4 qv, kv;
#pragma unroll
        for (int k = 0; k < 4; ++k) {
            int c = c0 + tx * 4 + k;
            float v = tile[tx * 4 + k][n];
            qv[k] = f2h(v * w_t[c] + b_t[c]);
            kv[k] = f2h(v * w_p[c] + b_p[c]);
        }
        size_t off = (size_t)(b * NN + n0 + n) * CC + c0 + tx * 4;
        *(us4*)&qf[off] = qv;
        *(us4*)&kf[off] = kv;
    }
}

// ---- flash attention: all operands in registers, one-iteration-ahead prefetch,
//      ZERO barriers in the K-loop. K+V tile = 32KB = L1-resident (4 waves share).
__global__ __launch_bounds__(256, 2) void attn(
    const unsigned short* __restrict__ qf, const unsigned short* __restrict__ kf,
    const unsigned short* __restrict__ vt,
    unsigned short* __restrict__ py, float2* __restrict__ pml,
    int keys_per) {
    __shared__ __align__(16) unsigned short p_s[4][16][40];  // wave-private P tiles

    // XCD-chunked swizzle: blocks sharing (s,b) (same K/V) land on one XCD.
    int bid = (int)((blockIdx.x & 7) * (gridDim.x >> 3) + (blockIdx.x >> 3));
    int s  = bid / (NB * 36);
    int r  = bid % (NB * 36);
    int b  = r / 36;
    int n0 = (r % 36) * 64;
    int t  = threadIdx.x;
    int w  = t >> 6;
    int l  = t & 63;
    int g  = l >> 4;
    int ln = l & 15;
    int k0 = s * keys_per;

    // Q fragments (A-operand): lane holds Q[n0+16w+ln][kb*32 + g*8 + j]
    half8 qh[8];
    {
        size_t base = (size_t)(b * NN + n0 + w * 16 + ln) * CC + g * 8;
#pragma unroll
        for (int kb = 0; kb < 8; ++kb)
            qh[kb] = *(const half8*)&qf[base + kb * 32];
    }

    f32x4 y[16];
#pragma unroll
    for (int ct = 0; ct < 16; ++ct) y[ct] = (f32x4){0.f, 0.f, 0.f, 0.f};
    float m_run[4] = {-1e30f, -1e30f, -1e30f, -1e30f};
    float l_run[4] = {0.f, 0.f, 0.f, 0.f};

    // per-wave operand registers: K 16 x half8, V 16 x half8
    half8 kr[16], vr[16];

    // lane-fixed base offsets
    size_t kbase0 = (size_t)(b * NN + k0 + ln) * CC + g * 8;        // key row ln
    size_t kbase1 = (size_t)(b * NN + k0 + 16 + ln) * CC + g * 8;   // key row 16+ln
    size_t vbase  = (size_t)(b * CC + ln) * NN + k0 + g * 8;        // V^T row ln (+ct*16 rows)

    // prologue: issue K(0), V(0)
#pragma unroll
    for (int kb = 0; kb < 8; ++kb) {
        kr[kb * 2 + 0] = *(const half8*)&kf[kbase0 + kb * 32];
        kr[kb * 2 + 1] = *(const half8*)&kf[kbase1 + kb * 32];
    }
#pragma unroll
    for (int ct = 0; ct < 16; ++ct)
        vr[ct] = *(const half8*)&vt[vbase + (size_t)ct * 16 * NN];

    int nkt = keys_per / TK;
    for (int kt = 0; kt < nkt; ++kt) {
        bool more = (kt + 1) < nkt;
        int moff = (kt + 1) * TK;                     // key offset of next tile
        size_t koff = (size_t)moff * CC;              // keys advance along ROWS of kf (stride CC)

        // S = Q K^T, fp16, 4 independent chains (waits on K prefetched last iter)
        f32x4 sa0 = (f32x4){0.f,0.f,0.f,0.f}, sb0 = sa0, sa1 = sa0, sb1 = sa0;
        __builtin_amdgcn_s_setprio(1);
#pragma unroll
        for (int k2 = 0; k2 < 4; ++k2) {
            int kA = k2 * 2, kB = k2 * 2 + 1;
            sa0 = MFMAH(qh[kA], kr[kA * 2 + 0], sa0);
            sa1 = MFMAH(qh[kA], kr[kA * 2 + 1], sa1);
            sb0 = MFMAH(qh[kB], kr[kB * 2 + 0], sb0);
            sb1 = MFMAH(qh[kB], kr[kB * 2 + 1], sb1);
        }
        __builtin_amdgcn_s_setprio(0);

        // K registers free -> issue next-tile K loads (hide under softmax+PV)
        if (more) {
#pragma unroll
            for (int kb = 0; kb < 8; ++kb) {
                kr[kb * 2 + 0] = *(const half8*)&kf[kbase0 + koff + kb * 32];
                kr[kb * 2 + 1] = *(const half8*)&kf[kbase1 + koff + kb * 32];
            }
        }

        f32x4 s0 = sa0 + sb0;
        f32x4 s1 = sa1 + sb1;

        // online softmax with defer-max (THR=8)
        float vmax[4];
#pragma unroll
        for (int j = 0; j < 4; ++j) {
            float v = fmaxf(s0[j], s1[j]);
            v = fmaxf(v, __shfl_xor(v, 1));
            v = fmaxf(v, __shfl_xor(v, 2));
            v = fmaxf(v, __shfl_xor(v, 4));
            v = fmaxf(v, __shfl_xor(v, 8));
            vmax[j] = v;
        }
        bool grow = (vmax[0] > m_run[0] + 8.f) | (vmax[1] > m_run[1] + 8.f) |
                    (vmax[2] > m_run[2] + 8.f) | (vmax[3] > m_run[3] + 8.f);
        if (__any(grow)) {
            float aj[4];
#pragma unroll
            for (int j = 0; j < 4; ++j) {
                float mnew = fmaxf(m_run[j], vmax[j]);
                aj[j] = __expf(m_run[j] - mnew);
                m_run[j] = mnew;
                l_run[j] *= aj[j];
            }
#pragma unroll
            for (int ct = 0; ct < 16; ++ct) {
                y[ct][0] *= aj[0]; y[ct][1] *= aj[1];
                y[ct][2] *= aj[2]; y[ct][3] *= aj[3];
            }
        }
#pragma unroll
        for (int j = 0; j < 4; ++j) {
            float p0 = __expf(s0[j] - m_run[j]);
            float p1 = __expf(s1[j] - m_run[j]);
            p_s[w][g * 4 + j][ln]      = f2h(p0);
            p_s[w][g * 4 + j][16 + ln] = f2h(p1);
            float ps = p0 + p1;
            ps += __shfl_xor(ps, 1);
            ps += __shfl_xor(ps, 2);
            ps += __shfl_xor(ps, 4);
            ps += __shfl_xor(ps, 8);
            l_run[j] += ps;
        }

        // PV (V prefetched last iteration; wave-private P via LDS round-trip)
        half8 pa = *(const half8*)&p_s[w][ln][g * 8];
        __builtin_amdgcn_s_setprio(1);
#pragma unroll
        for (int ct = 0; ct < 16; ++ct)
            y[ct] = MFMAH(pa, vr[ct], y[ct]);
        __builtin_amdgcn_s_setprio(0);

        // V registers free -> issue next-tile V loads (keys stride 1 in vt)
        if (more) {
#pragma unroll
            for (int ct = 0; ct < 16; ++ct)
                vr[ct] = *(const half8*)&vt[vbase + moff + (size_t)ct * 16 * NN];
        }
    }

    // write unnormalized partial y (bf16) + per-row (m, l)
#pragma unroll
    for (int j = 0; j < 4; ++j) {
        int n = n0 + w * 16 + g * 4 + j;
        size_t rowb = ((size_t)(s * NB + b) * NN + n) * CC;
#pragma unroll
        for (int ct = 0; ct < 16; ++ct)
            py[rowb + ct * 16 + ln] = f2bf(y[ct][j]);
        if (ln == 0)
            pml[(size_t)(s * NB + b) * NN + n] = make_float2(m_run[j], l_run[j]);
    }
}

// ---- combine splits + out-proj/BN/residual; out layout (B,C,N) ----
__global__ __launch_bounds__(256) void combine(
    const unsigned short* __restrict__ py, const float2* __restrict__ pml,
    const float* __restrict__ x, const float* __restrict__ s2b2,
    float* __restrict__ out, int S) {
    __shared__ float ptile[64][65];
    int bid = blockIdx.x;
    int b  = bid / 36;
    int n0 = (bid % 36) * 64;
    int t  = threadIdx.x;
    int w  = t >> 6;
    int l  = t & 63;
    int n  = n0 + l;

    float M = -1e30f;
    for (int s = 0; s < S; ++s)
        M = fmaxf(M, pml[(size_t)(s * NB + b) * NN + n].x);
    float L = 0.f;
    for (int s = 0; s < S; ++s) {
        float2 ml = pml[(size_t)(s * NB + b) * NN + n];
        L += ml.y * __expf(ml.x - M);
    }

    float acc[64];
#pragma unroll
    for (int a = 0; a < 64; ++a) acc[a] = 0.f;

    for (int s = 0; s < S; ++s) {
        float wgt = __expf(pml[(size_t)(s * NB + b) * NN + n].x - M);
#pragma unroll
        for (int cc = 0; cc < 4; ++cc) {
            __syncthreads();
#pragma unroll
            for (int i = 0; i < 4; ++i) {
                int u = i * 256 + t;
                int row = u >> 4, c4 = (u & 15) * 4;
                us4 v = *(const us4*)&py[((size_t)(s * NB + b) * NN + n0 + row) * CC + cc * 64 + c4];
                ptile[row][c4 + 0] = bf2f(v[0]);
                ptile[row][c4 + 1] = bf2f(v[1]);
                ptile[row][c4 + 2] = bf2f(v[2]);
                ptile[row][c4 + 3] = bf2f(v[3]);
            }
            __syncthreads();
#pragma unroll
            for (int i = 0; i < 16; ++i)
                acc[cc * 16 + i] += wgt * ptile[l][w * 16 + i];
        }
    }

    float invL = 1.f / L;
#pragma unroll
    for (int cc = 0; cc < 4; ++cc) {
#pragma unroll
        for (int i = 0; i < 16; ++i) {
            int c = cc * 64 + w * 16 + i;
            size_t idx = ((size_t)b * CC + c) * NN + n;
            out[idx] = acc[cc * 16 + i] * invL * s2b2[c] + s2b2[CC + c] + x[idx];
        }
    }
}

extern "C" void kernel_launch(void* const* d_in, const int* in_sizes, int n_in,
                              void* d_out, int out_size, void* d_ws, size_t ws_size,
                              hipStream_t stream) {
    const float* x   = (const float*)d_in[0];
    const float* w_g = (const float*)d_in[1];
    const float* b_g = (const float*)d_in[2];
    const float* w_t = (const float*)d_in[3];
    const float* b_t = (const float*)d_in[4];
    const float* w_p = (const float*)d_in[5];
    const float* b_p = (const float*)d_in[6];
    const float* w_o = (const float*)d_in[7];
    const float* b_o = (const float*)d_in[8];
    const float* gam = (const float*)d_in[9];
    const float* bet = (const float*)d_in[10];
    const float* mea = (const float*)d_in[11];
    const float* var = (const float*)d_in[12];
    float* out = (float*)d_out;

    unsigned short* qf = (unsigned short*)d_ws;
    unsigned short* kf = qf + QSZ;
    unsigned short* vt = kf + QSZ;
    float* s2b2 = (float*)(vt + QSZ);

    size_t base_b = 3 * QSZ * 2 + 2048;
    size_t per_b  = QSZ * 2 + (size_t)NB * NN * 8;
    int S = 1;
    if (base_b + 4 * per_b <= ws_size) S = 4;
    else if (base_b + 2 * per_b <= ws_size) S = 2;

    float2* pml = (float2*)((char*)d_ws + base_b);
    unsigned short* py = (unsigned short*)(pml + (size_t)S * NB * NN);

    prep_s2<<<1, 256, 0, stream>>>(w_o, b_o, gam, bet, mea, var, s2b2);
    prep_v<<<(int)(QSZ / 2048), 256, 0, stream>>>(x, w_g, b_g, vt);
    prep_qk<<<NB * 36 * 4, 256, 0, stream>>>(x, w_t, b_t, w_p, b_p, qf, kf);
    attn<<<NB * 36 * S, 256, 0, stream>>>(qf, kf, vt, py, pml, NN / S);
    combine<<<NB * 36, 256, 0, stream>>>(py, pml, x, s2b2, out, S);
}

// Round 14
// 172.055 us; speedup vs baseline: 2.3321x; 2.3321x over previous
//
#include <hip/hip_runtime.h>
#include <hip/hip_fp16.h>

#define NB 8
#define CC 256
#define NN 2304
#define TK 32
#define QSZ ((size_t)NB * NN * CC)

typedef __attribute__((ext_vector_type(8))) _Float16 half8;
typedef __attribute__((ext_vector_type(4))) float f32x4;
typedef __attribute__((ext_vector_type(4))) unsigned short us4;

#define MFMAH(a, b, c) __builtin_amdgcn_mfma_f32_16x16x32_f16((a), (b), (c), 0, 0, 0)

__device__ __forceinline__ unsigned short f2h(float f) {
    union { _Float16 x; unsigned short u; } c;
    c.x = (_Float16)f;
    return c.u;
}
__device__ __forceinline__ unsigned short f2bf(float f) {
    unsigned int u = __float_as_uint(f);
    u = (u + 0x7fffu + ((u >> 16) & 1u)) >> 16;
    return (unsigned short)u;
}
__device__ __forceinline__ float bf2f(unsigned short h) {
    return __uint_as_float(((unsigned int)h) << 16);
}

// ---- fold output projection + BN into per-channel scale/bias ----
__global__ void prep_s2(const float* __restrict__ w_o, const float* __restrict__ b_o,
                        const float* __restrict__ gam, const float* __restrict__ bet,
                        const float* __restrict__ mea, const float* __restrict__ var,
                        float* __restrict__ s2b2) {
    int c = threadIdx.x;
    float inv = gam[c] * rsqrtf(var[c] + 1e-5f);
    s2b2[c]      = w_o[c] * inv;
    s2b2[CC + c] = b_o[c] * inv + bet[c] - mea[c] * inv;
}

// ---- V^T projection: vt[b][c][m] = fp16(x * w_g + b_g) ----
__global__ __launch_bounds__(256) void prep_v(const float* __restrict__ x,
                                              const float* __restrict__ w_g,
                                              const float* __restrict__ b_g,
                                              unsigned short* __restrict__ vt) {
    size_t i = ((size_t)blockIdx.x * 256 + threadIdx.x) * 8;
    int c = (int)((i / NN) % CC);
    float wg = w_g[c], bg = b_g[c];
    float4 a = *(const float4*)&x[i];
    float4 d = *(const float4*)&x[i + 4];
    us4 o0, o1;
    o0[0] = f2h(a.x * wg + bg); o0[1] = f2h(a.y * wg + bg);
    o0[2] = f2h(a.z * wg + bg); o0[3] = f2h(a.w * wg + bg);
    o1[0] = f2h(d.x * wg + bg); o1[1] = f2h(d.y * wg + bg);
    o1[2] = f2h(d.z * wg + bg); o1[3] = f2h(d.w * wg + bg);
    *(us4*)&vt[i]     = o0;
    *(us4*)&vt[i + 4] = o1;
}

// ---- transpose + project x -> Q, K fp16, layout (B, N, C) ----
__global__ __launch_bounds__(256) void prep_qk(
    const float* __restrict__ x,
    const float* __restrict__ w_t, const float* __restrict__ b_t,
    const float* __restrict__ w_p, const float* __restrict__ b_p,
    unsigned short* __restrict__ qf, unsigned short* __restrict__ kf) {
    __shared__ float tile[64][65];
    int bid = blockIdx.x;
    int b  = bid / 144;
    int r  = bid % 144;
    int n0 = (r / 4) * 64;
    int c0 = (r % 4) * 64;
    int t  = threadIdx.x;
    int tx = t & 15, ty = t >> 4;

#pragma unroll
    for (int i = 0; i < 4; ++i) {
        int c = ty + i * 16;
        const float4 v = *(const float4*)&x[(size_t)(b * CC + c0 + c) * NN + n0 + tx * 4];
        tile[c][tx * 4 + 0] = v.x;
        tile[c][tx * 4 + 1] = v.y;
        tile[c][tx * 4 + 2] = v.z;
        tile[c][tx * 4 + 3] = v.w;
    }
    __syncthreads();
#pragma unroll
    for (int i = 0; i < 4; ++i) {
        int n = ty + i * 16;
        us4 qv, kv;
#pragma unroll
        for (int k = 0; k < 4; ++k) {
            int c = c0 + tx * 4 + k;
            float v = tile[tx * 4 + k][n];
            qv[k] = f2h(v * w_t[c] + b_t[c]);
            kv[k] = f2h(v * w_p[c] + b_p[c]);
        }
        size_t off = (size_t)(b * NN + n0 + n) * CC + c0 + tx * 4;
        *(us4*)&qf[off] = qv;
        *(us4*)&kf[off] = kv;
    }
}

// ---- flash attention: 512 threads / 8 waves / 128 q-rows per block,
//      LDS-staged K,V with reg-staged async prefetch (R10 structure, 2x work/block) ----
__global__ __launch_bounds__(512, 2) void attn(
    const unsigned short* __restrict__ qf, const unsigned short* __restrict__ kf,
    const unsigned short* __restrict__ vt,
    unsigned short* __restrict__ py, float2* __restrict__ pml,
    int keys_per) {
    __shared__ __align__(16) unsigned short kh_s[TK][264];   // K fp16, padded
    __shared__ __align__(16) unsigned short vt_s[CC][40];    // V^T fp16
    __shared__ __align__(16) unsigned short p_s[8][16][40];  // P fp16 per wave

    // XCD-chunked swizzle: blocks sharing (s,b) (same K/V) land on one XCD.
    int bid = (int)((blockIdx.x & 7) * (gridDim.x >> 3) + (blockIdx.x >> 3));
    int s  = bid / (NB * 18);
    int r  = bid % (NB * 18);
    int b  = r / 18;
    int n0 = (r % 18) * 128;
    int t  = threadIdx.x;
    int w  = t >> 6;          // 0..7
    int l  = t & 63;
    int g  = l >> 4;
    int ln = l & 15;
    int k0 = s * keys_per;

    // Q fragments (A-operand): lane holds Q[n0+16w+ln][kb*32 + g*8 + j]
    half8 qh[8];
    {
        size_t base = (size_t)(b * NN + n0 + w * 16 + ln) * CC + g * 8;
#pragma unroll
        for (int kb = 0; kb < 8; ++kb)
            qh[kb] = *(const half8*)&qf[base + kb * 32];
    }

    f32x4 y[16];
#pragma unroll
    for (int ct = 0; ct < 16; ++ct) y[ct] = (f32x4){0.f, 0.f, 0.f, 0.f};
    float m_run[4] = {-1e30f, -1e30f, -1e30f, -1e30f};
    float l_run[4] = {0.f, 0.f, 0.f, 0.f};

    // register staging (next tile): 2 units each of K and V per thread
    half8 skh[2], svv[2];

    // load + store tile 0
#pragma unroll
    for (int i = 0; i < 2; ++i) {
        int u = i * 512 + t;
        int row = u >> 5, col = (u & 31) * 8;
        skh[i] = *(const half8*)&kf[(size_t)(b * NN + k0 + row) * CC + col];
        int c = u >> 2, mq = (u & 3) * 8;
        svv[i] = *(const half8*)&vt[(size_t)(b * CC + c) * NN + k0 + mq];
    }
#pragma unroll
    for (int i = 0; i < 2; ++i) {
        int u = i * 512 + t;
        int row = u >> 5, col = (u & 31) * 8;
        *(half8*)&kh_s[row][col] = skh[i];
        int c = u >> 2, mq = (u & 3) * 8;
        *(half8*)&vt_s[c][mq] = svv[i];
    }
    __syncthreads();

    int nkt = keys_per / TK;
    for (int kt = 0; kt < nkt; ++kt) {
        bool more = (kt + 1) < nkt;
        if (more) {   // issue next-tile loads; complete under compute (T14)
            int m1 = k0 + (kt + 1) * TK;
#pragma unroll
            for (int i = 0; i < 2; ++i) {
                int u = i * 512 + t;
                int row = u >> 5, col = (u & 31) * 8;
                skh[i] = *(const half8*)&kf[(size_t)(b * NN + m1 + row) * CC + col];
                int c = u >> 2, mq = (u & 3) * 8;
                svv[i] = *(const half8*)&vt[(size_t)(b * CC + c) * NN + m1 + mq];
            }
        }

        // S = Q K^T, fp16, 4 independent chains (2 row-halves x even/odd kb)
        f32x4 sa0 = (f32x4){0.f,0.f,0.f,0.f}, sb0 = sa0, sa1 = sa0, sb1 = sa0;
        __builtin_amdgcn_s_setprio(1);
#pragma unroll
        for (int k2 = 0; k2 < 4; ++k2) {
            int kA = k2 * 2, kB = k2 * 2 + 1;
            half8 bA0 = *(const half8*)&kh_s[ln][kA * 32 + g * 8];
            half8 bA1 = *(const half8*)&kh_s[16 + ln][kA * 32 + g * 8];
            half8 bB0 = *(const half8*)&kh_s[ln][kB * 32 + g * 8];
            half8 bB1 = *(const half8*)&kh_s[16 + ln][kB * 32 + g * 8];
            sa0 = MFMAH(qh[kA], bA0, sa0);
            sa1 = MFMAH(qh[kA], bA1, sa1);
            sb0 = MFMAH(qh[kB], bB0, sb0);
            sb1 = MFMAH(qh[kB], bB1, sb1);
        }
        __builtin_amdgcn_s_setprio(0);
        f32x4 s0 = sa0 + sb0;
        f32x4 s1 = sa1 + sb1;

        // online softmax with defer-max (THR=8)
        float vmax[4];
#pragma unroll
        for (int j = 0; j < 4; ++j) {
            float v = fmaxf(s0[j], s1[j]);
            v = fmaxf(v, __shfl_xor(v, 1));
            v = fmaxf(v, __shfl_xor(v, 2));
            v = fmaxf(v, __shfl_xor(v, 4));
            v = fmaxf(v, __shfl_xor(v, 8));
            vmax[j] = v;
        }
        bool grow = (vmax[0] > m_run[0] + 8.f) | (vmax[1] > m_run[1] + 8.f) |
                    (vmax[2] > m_run[2] + 8.f) | (vmax[3] > m_run[3] + 8.f);
        if (__any(grow)) {
            float aj[4];
#pragma unroll
            for (int j = 0; j < 4; ++j) {
                float mnew = fmaxf(m_run[j], vmax[j]);
                aj[j] = __expf(m_run[j] - mnew);
                m_run[j] = mnew;
                l_run[j] *= aj[j];
            }
#pragma unroll
            for (int ct = 0; ct < 16; ++ct) {
                y[ct][0] *= aj[0]; y[ct][1] *= aj[1];
                y[ct][2] *= aj[2]; y[ct][3] *= aj[3];
            }
        }
#pragma unroll
        for (int j = 0; j < 4; ++j) {
            float p0 = __expf(s0[j] - m_run[j]);
            float p1 = __expf(s1[j] - m_run[j]);
            p_s[w][g * 4 + j][ln]      = f2h(p0);
            p_s[w][g * 4 + j][16 + ln] = f2h(p1);
            float ps = p0 + p1;
            ps += __shfl_xor(ps, 1);
            ps += __shfl_xor(ps, 2);
            ps += __shfl_xor(ps, 4);
            ps += __shfl_xor(ps, 8);
            l_run[j] += ps;
        }

        // PV (fp16)
        half8 pa = *(const half8*)&p_s[w][ln][g * 8];
        __builtin_amdgcn_s_setprio(1);
#pragma unroll
        for (int ct = 0; ct < 16; ++ct) {
            half8 vb = *(const half8*)&vt_s[ct * 16 + ln][g * 8];
            y[ct] = MFMAH(pa, vb, y[ct]);
        }
        __builtin_amdgcn_s_setprio(0);

        if (more) {
            __syncthreads();   // all waves done reading current LDS tile
#pragma unroll
            for (int i = 0; i < 2; ++i) {
                int u = i * 512 + t;
                int row = u >> 5, col = (u & 31) * 8;
                *(half8*)&kh_s[row][col] = skh[i];
                int c = u >> 2, mq = (u & 3) * 8;
                *(half8*)&vt_s[c][mq] = svv[i];
            }
            __syncthreads();   // tile ready
        }
    }

    // write unnormalized partial y (bf16) + per-row (m, l)
#pragma unroll
    for (int j = 0; j < 4; ++j) {
        int n = n0 + w * 16 + g * 4 + j;
        size_t rowb = ((size_t)(s * NB + b) * NN + n) * CC;
#pragma unroll
        for (int ct = 0; ct < 16; ++ct)
            py[rowb + ct * 16 + ln] = f2bf(y[ct][j]);
        if (ln == 0)
            pml[(size_t)(s * NB + b) * NN + n] = make_float2(m_run[j], l_run[j]);
    }
}

// ---- combine splits + out-proj/BN/residual; out layout (B,C,N) ----
__global__ __launch_bounds__(256) void combine(
    const unsigned short* __restrict__ py, const float2* __restrict__ pml,
    const float* __restrict__ x, const float* __restrict__ s2b2,
    float* __restrict__ out, int S) {
    __shared__ float ptile[64][65];
    int bid = blockIdx.x;
    int b  = bid / 36;
    int n0 = (bid % 36) * 64;
    int t  = threadIdx.x;
    int w  = t >> 6;
    int l  = t & 63;
    int n  = n0 + l;

    float M = -1e30f;
    for (int s = 0; s < S; ++s)
        M = fmaxf(M, pml[(size_t)(s * NB + b) * NN + n].x);
    float L = 0.f;
    for (int s = 0; s < S; ++s) {
        float2 ml = pml[(size_t)(s * NB + b) * NN + n];
        L += ml.y * __expf(ml.x - M);
    }

    float acc[64];
#pragma unroll
    for (int a = 0; a < 64; ++a) acc[a] = 0.f;

    for (int s = 0; s < S; ++s) {
        float wgt = __expf(pml[(size_t)(s * NB + b) * NN + n].x - M);
#pragma unroll
        for (int cc = 0; cc < 4; ++cc) {
            __syncthreads();
#pragma unroll
            for (int i = 0; i < 4; ++i) {
                int u = i * 256 + t;
                int row = u >> 4, c4 = (u & 15) * 4;
                us4 v = *(const us4*)&py[((size_t)(s * NB + b) * NN + n0 + row) * CC + cc * 64 + c4];
                ptile[row][c4 + 0] = bf2f(v[0]);
                ptile[row][c4 + 1] = bf2f(v[1]);
                ptile[row][c4 + 2] = bf2f(v[2]);
                ptile[row][c4 + 3] = bf2f(v[3]);
            }
            __syncthreads();
#pragma unroll
            for (int i = 0; i < 16; ++i)
                acc[cc * 16 + i] += wgt * ptile[l][w * 16 + i];
        }
    }

    float invL = 1.f / L;
#pragma unroll
    for (int cc = 0; cc < 4; ++cc) {
#pragma unroll
        for (int i = 0; i < 16; ++i) {
            int c = cc * 64 + w * 16 + i;
            size_t idx = ((size_t)b * CC + c) * NN + n;
            out[idx] = acc[cc * 16 + i] * invL * s2b2[c] + s2b2[CC + c] + x[idx];
        }
    }
}

extern "C" void kernel_launch(void* const* d_in, const int* in_sizes, int n_in,
                              void* d_out, int out_size, void* d_ws, size_t ws_size,
                              hipStream_t stream) {
    const float* x   = (const float*)d_in[0];
    const float* w_g = (const float*)d_in[1];
    const float* b_g = (const float*)d_in[2];
    const float* w_t = (const float*)d_in[3];
    const float* b_t = (const float*)d_in[4];
    const float* w_p = (const float*)d_in[5];
    const float* b_p = (const float*)d_in[6];
    const float* w_o = (const float*)d_in[7];
    const float* b_o = (const float*)d_in[8];
    const float* gam = (const float*)d_in[9];
    const float* bet = (const float*)d_in[10];
    const float* mea = (const float*)d_in[11];
    const float* var = (const float*)d_in[12];
    float* out = (float*)d_out;

    unsigned short* qf = (unsigned short*)d_ws;
    unsigned short* kf = qf + QSZ;
    unsigned short* vt = kf + QSZ;
    float* s2b2 = (float*)(vt + QSZ);

    size_t base_b = 3 * QSZ * 2 + 2048;
    size_t per_b  = QSZ * 2 + (size_t)NB * NN * 8;
    int S = 1;
    if (base_b + 4 * per_b <= ws_size) S = 4;
    else if (base_b + 2 * per_b <= ws_size) S = 2;

    float2* pml = (float2*)((char*)d_ws + base_b);
    unsigned short* py = (unsigned short*)(pml + (size_t)S * NB * NN);

    prep_s2<<<1, 256, 0, stream>>>(w_o, b_o, gam, bet, mea, var, s2b2);
    prep_v<<<(int)(QSZ / 2048), 256, 0, stream>>>(x, w_g, b_g, vt);
    prep_qk<<<NB * 36 * 4, 256, 0, stream>>>(x, w_t, b_t, w_p, b_p, qf, kf);
    attn<<<NB * 18 * S, 512, 0, stream>>>(qf, kf, vt, py, pml, NN / S);
    combine<<<NB * 36, 256, 0, stream>>>(py, pml, x, s2b2, out, S);
}

// Round 15
// 141.435 us; speedup vs baseline: 2.8370x; 1.2165x over previous
//
#include <hip/hip_runtime.h>
#include <hip/hip_fp16.h>

#define NB 8
#define CC 256
#define NN 2304
#define TK 32
#define QSZ ((size_t)NB * NN * CC)

typedef __attribute__((ext_vector_type(8))) _Float16 half8;
typedef __attribute__((ext_vector_type(4))) float f32x4;
typedef __attribute__((ext_vector_type(4))) unsigned short us4;

#define MFMAH(a, b, c) __builtin_amdgcn_mfma_f32_16x16x32_f16((a), (b), (c), 0, 0, 0)

__device__ __forceinline__ unsigned short f2h(float f) {
    union { _Float16 x; unsigned short u; } c;
    c.x = (_Float16)f;
    return c.u;
}
__device__ __forceinline__ unsigned short f2bf(float f) {
    unsigned int u = __float_as_uint(f);
    u = (u + 0x7fffu + ((u >> 16) & 1u)) >> 16;
    return (unsigned short)u;
}
__device__ __forceinline__ float bf2f(unsigned short h) {
    return __uint_as_float(((unsigned int)h) << 16);
}

// ---- fold output projection + BN into per-channel scale/bias ----
__global__ void prep_s2(const float* __restrict__ w_o, const float* __restrict__ b_o,
                        const float* __restrict__ gam, const float* __restrict__ bet,
                        const float* __restrict__ mea, const float* __restrict__ var,
                        float* __restrict__ s2b2) {
    int c = threadIdx.x;
    float inv = gam[c] * rsqrtf(var[c] + 1e-5f);
    s2b2[c]      = w_o[c] * inv;
    s2b2[CC + c] = b_o[c] * inv + bet[c] - mea[c] * inv;
}

// ---- V^T projection: vt[b][c][m] = fp16(x * w_g + b_g) ----
__global__ __launch_bounds__(256) void prep_v(const float* __restrict__ x,
                                              const float* __restrict__ w_g,
                                              const float* __restrict__ b_g,
                                              unsigned short* __restrict__ vt) {
    size_t i = ((size_t)blockIdx.x * 256 + threadIdx.x) * 8;
    int c = (int)((i / NN) % CC);
    float wg = w_g[c], bg = b_g[c];
    float4 a = *(const float4*)&x[i];
    float4 d = *(const float4*)&x[i + 4];
    us4 o0, o1;
    o0[0] = f2h(a.x * wg + bg); o0[1] = f2h(a.y * wg + bg);
    o0[2] = f2h(a.z * wg + bg); o0[3] = f2h(a.w * wg + bg);
    o1[0] = f2h(d.x * wg + bg); o1[1] = f2h(d.y * wg + bg);
    o1[2] = f2h(d.z * wg + bg); o1[3] = f2h(d.w * wg + bg);
    *(us4*)&vt[i]     = o0;
    *(us4*)&vt[i + 4] = o1;
}

// ---- transpose + project x -> Q, K fp16, layout (B, N, C) ----
__global__ __launch_bounds__(256) void prep_qk(
    const float* __restrict__ x,
    const float* __restrict__ w_t, const float* __restrict__ b_t,
    const float* __restrict__ w_p, const float* __restrict__ b_p,
    unsigned short* __restrict__ qf, unsigned short* __restrict__ kf) {
    __shared__ float tile[64][65];
    int bid = blockIdx.x;
    int b  = bid / 144;
    int r  = bid % 144;
    int n0 = (r / 4) * 64;
    int c0 = (r % 4) * 64;
    int t  = threadIdx.x;
    int tx = t & 15, ty = t >> 4;

#pragma unroll
    for (int i = 0; i < 4; ++i) {
        int c = ty + i * 16;
        const float4 v = *(const float4*)&x[(size_t)(b * CC + c0 + c) * NN + n0 + tx * 4];
        tile[c][tx * 4 + 0] = v.x;
        tile[c][tx * 4 + 1] = v.y;
        tile[c][tx * 4 + 2] = v.z;
        tile[c][tx * 4 + 3] = v.w;
    }
    __syncthreads();
#pragma unroll
    for (int i = 0; i < 4; ++i) {
        int n = ty + i * 16;
        us4 qv, kv;
#pragma unroll
        for (int k = 0; k < 4; ++k) {
            int c = c0 + tx * 4 + k;
            float v = tile[tx * 4 + k][n];
            qv[k] = f2h(v * w_t[c] + b_t[c]);
            kv[k] = f2h(v * w_p[c] + b_p[c]);
        }
        size_t off = (size_t)(b * NN + n0 + n) * CC + c0 + tx * 4;
        *(us4*)&qf[off] = qv;
        *(us4*)&kf[off] = kv;
    }
}

// ---- flash attention: swapped QK^T (S^T[key][q], q lane-local) + fp16 PV,
//      key-split, LDS-staged K/V with reg-staged async prefetch ----
__global__ __launch_bounds__(256, 2) void attn(
    const unsigned short* __restrict__ qf, const unsigned short* __restrict__ kf,
    const unsigned short* __restrict__ vt,
    unsigned short* __restrict__ py, float2* __restrict__ pml,
    int keys_per) {
    __shared__ __align__(16) unsigned short kh_s[TK][264];   // K fp16, padded
    __shared__ __align__(16) unsigned short vt_s[CC][40];    // V^T fp16
    __shared__ __align__(16) unsigned short p_s[4][16][40];  // P fp16 per wave

    // XCD-chunked swizzle: blocks sharing (s,b) (same K/V) land on one XCD.
    int bid = (int)((blockIdx.x & 7) * (gridDim.x >> 3) + (blockIdx.x >> 3));
    int s  = bid / (NB * 36);
    int r  = bid % (NB * 36);
    int b  = r / 36;
    int n0 = (r % 36) * 64;
    int t  = threadIdx.x;
    int w  = t >> 6;
    int l  = t & 63;
    int g  = l >> 4;
    int ln = l & 15;
    int k0 = s * keys_per;

    // Q fragments: lane holds Q[n0+16w+ln][kb*32 + g*8 + j] (serves as B-operand after swap)
    half8 qh[8];
    {
        size_t base = (size_t)(b * NN + n0 + w * 16 + ln) * CC + g * 8;
#pragma unroll
        for (int kb = 0; kb < 8; ++kb)
            qh[kb] = *(const half8*)&qf[base + kb * 32];
    }

    f32x4 y[16];
#pragma unroll
    for (int ct = 0; ct < 16; ++ct) y[ct] = (f32x4){0.f, 0.f, 0.f, 0.f};
    float m_run = -1e30f;   // per-lane: q-row = ln
    float l_run = 0.f;

    // register staging (next tile)
    half8 skh[4], svv[4];

    // load + store tile 0
#pragma unroll
    for (int i = 0; i < 4; ++i) {
        int u = i * 256 + t;
        int row = u >> 5, col = (u & 31) * 8;
        skh[i] = *(const half8*)&kf[(size_t)(b * NN + k0 + row) * CC + col];
        int c = u >> 2, mq = (u & 3) * 8;
        svv[i] = *(const half8*)&vt[(size_t)(b * CC + c) * NN + k0 + mq];
    }
#pragma unroll
    for (int i = 0; i < 4; ++i) {
        int u = i * 256 + t;
        int row = u >> 5, col = (u & 31) * 8;
        *(half8*)&kh_s[row][col] = skh[i];
        int c = u >> 2, mq = (u & 3) * 8;
        *(half8*)&vt_s[c][mq] = svv[i];
    }
    __syncthreads();

    int nkt = keys_per / TK;
    for (int kt = 0; kt < nkt; ++kt) {
        bool more = (kt + 1) < nkt;
        if (more) {   // issue next-tile loads; complete under compute (T14)
            int m1 = k0 + (kt + 1) * TK;
#pragma unroll
            for (int i = 0; i < 4; ++i) {
                int u = i * 256 + t;
                int row = u >> 5, col = (u & 31) * 8;
                skh[i] = *(const half8*)&kf[(size_t)(b * NN + m1 + row) * CC + col];
                int c = u >> 2, mq = (u & 3) * 8;
                svv[i] = *(const half8*)&vt[(size_t)(b * CC + c) * NN + m1 + mq];
            }
        }

        // S^T = K Q^T (swapped operands; same LDS/register reads as before):
        // s0[reg] = S[key=g*4+reg][q=ln], s1[reg] = S[key=16+g*4+reg][q=ln]
        f32x4 sa0 = (f32x4){0.f,0.f,0.f,0.f}, sb0 = sa0, sa1 = sa0, sb1 = sa0;
        __builtin_amdgcn_s_setprio(1);
#pragma unroll
        for (int k2 = 0; k2 < 4; ++k2) {
            int kA = k2 * 2, kB = k2 * 2 + 1;
            half8 bA0 = *(const half8*)&kh_s[ln][kA * 32 + g * 8];
            half8 bA1 = *(const half8*)&kh_s[16 + ln][kA * 32 + g * 8];
            half8 bB0 = *(const half8*)&kh_s[ln][kB * 32 + g * 8];
            half8 bB1 = *(const half8*)&kh_s[16 + ln][kB * 32 + g * 8];
            sa0 = MFMAH(bA0, qh[kA], sa0);
            sa1 = MFMAH(bA1, qh[kA], sa1);
            sb0 = MFMAH(bB0, qh[kB], sb0);
            sb1 = MFMAH(bB1, qh[kB], sb1);
        }
        __builtin_amdgcn_s_setprio(0);
        f32x4 s0 = sa0 + sb0;
        f32x4 s1 = sa1 + sb1;

        // row-softmax: q=ln is lane-local -> 7 local fmax + 2 shfl (xor16, xor32)
        float vmax = fmaxf(fmaxf(fmaxf(s0[0], s0[1]), fmaxf(s0[2], s0[3])),
                           fmaxf(fmaxf(s1[0], s1[1]), fmaxf(s1[2], s1[3])));
        vmax = fmaxf(vmax, __shfl_xor(vmax, 16));
        vmax = fmaxf(vmax, __shfl_xor(vmax, 32));
        // defer-max (THR=8)
        if (__any(vmax > m_run + 8.f)) {
            float mnew  = fmaxf(m_run, vmax);
            float alpha = __expf(m_run - mnew);
            m_run = mnew;
            l_run *= alpha;
            float aj[4];
#pragma unroll
            for (int j = 0; j < 4; ++j) aj[j] = __shfl(alpha, g * 4 + j);
#pragma unroll
            for (int ct = 0; ct < 16; ++ct) {
                y[ct][0] *= aj[0]; y[ct][1] *= aj[1];
                y[ct][2] *= aj[2]; y[ct][3] *= aj[3];
            }
        }
        // P = exp(S - m): 8 lane-local values; packed 8B LDS writes
        us4 plo, phi;
        float psum = 0.f;
#pragma unroll
        for (int j = 0; j < 4; ++j) {
            float p0 = __expf(s0[j] - m_run);
            float p1 = __expf(s1[j] - m_run);
            plo[j] = f2h(p0);
            phi[j] = f2h(p1);
            psum += p0 + p1;
        }
        *(us4*)&p_s[w][ln][g * 4]      = plo;   // keys g*4..g*4+3
        *(us4*)&p_s[w][ln][16 + g * 4] = phi;   // keys 16+g*4..+3
        psum += __shfl_xor(psum, 16);
        psum += __shfl_xor(psum, 32);
        l_run += psum;

        // PV (A = P from wave-private LDS; same fragment read as before)
        half8 pa = *(const half8*)&p_s[w][ln][g * 8];
        __builtin_amdgcn_s_setprio(1);
#pragma unroll
        for (int ct = 0; ct < 16; ++ct) {
            half8 vb = *(const half8*)&vt_s[ct * 16 + ln][g * 8];
            y[ct] = MFMAH(pa, vb, y[ct]);
        }
        __builtin_amdgcn_s_setprio(0);

        if (more) {
            __syncthreads();   // all waves done reading current LDS tile
#pragma unroll
            for (int i = 0; i < 4; ++i) {
                int u = i * 256 + t;
                int row = u >> 5, col = (u & 31) * 8;
                *(half8*)&kh_s[row][col] = skh[i];
                int c = u >> 2, mq = (u & 3) * 8;
                *(half8*)&vt_s[c][mq] = svv[i];
            }
            __syncthreads();   // tile ready
        }
    }

    // write unnormalized partial y (bf16) + per-row (m, l); (m,l) lives at q=ln
#pragma unroll
    for (int j = 0; j < 4; ++j) {
        int n = n0 + w * 16 + g * 4 + j;
        size_t rowb = ((size_t)(s * NB + b) * NN + n) * CC;
#pragma unroll
        for (int ct = 0; ct < 16; ++ct)
            py[rowb + ct * 16 + ln] = f2bf(y[ct][j]);
    }
    if (g == 0)
        pml[(size_t)(s * NB + b) * NN + n0 + w * 16 + ln] = make_float2(m_run, l_run);
}

// ---- combine splits + out-proj/BN/residual; out layout (B,C,N) ----
__global__ __launch_bounds__(256) void combine(
    const unsigned short* __restrict__ py, const float2* __restrict__ pml,
    const float* __restrict__ x, const float* __restrict__ s2b2,
    float* __restrict__ out, int S) {
    __shared__ float ptile[64][65];
    int bid = blockIdx.x;
    int b  = bid / 36;
    int n0 = (bid % 36) * 64;
    int t  = threadIdx.x;
    int w  = t >> 6;
    int l  = t & 63;
    int n  = n0 + l;

    float M = -1e30f;
    for (int s = 0; s < S; ++s)
        M = fmaxf(M, pml[(size_t)(s * NB + b) * NN + n].x);
    float L = 0.f;
    for (int s = 0; s < S; ++s) {
        float2 ml = pml[(size_t)(s * NB + b) * NN + n];
        L += ml.y * __expf(ml.x - M);
    }

    float acc[64];
#pragma unroll
    for (int a = 0; a < 64; ++a) acc[a] = 0.f;

    for (int s = 0; s < S; ++s) {
        float wgt = __expf(pml[(size_t)(s * NB + b) * NN + n].x - M);
#pragma unroll
        for (int cc = 0; cc < 4; ++cc) {
            __syncthreads();
#pragma unroll
            for (int i = 0; i < 4; ++i) {
                int u = i * 256 + t;
                int row = u >> 4, c4 = (u & 15) * 4;
                us4 v = *(const us4*)&py[((size_t)(s * NB + b) * NN + n0 + row) * CC + cc * 64 + c4];
                ptile[row][c4 + 0] = bf2f(v[0]);
                ptile[row][c4 + 1] = bf2f(v[1]);
                ptile[row][c4 + 2] = bf2f(v[2]);
                ptile[row][c4 + 3] = bf2f(v[3]);
            }
            __syncthreads();
#pragma unroll
            for (int i = 0; i < 16; ++i)
                acc[cc * 16 + i] += wgt * ptile[l][w * 16 + i];
        }
    }

    float invL = 1.f / L;
#pragma unroll
    for (int cc = 0; cc < 4; ++cc) {
#pragma unroll
        for (int i = 0; i < 16; ++i) {
            int c = cc * 64 + w * 16 + i;
            size_t idx = ((size_t)b * CC + c) * NN + n;
            out[idx] = acc[cc * 16 + i] * invL * s2b2[c] + s2b2[CC + c] + x[idx];
        }
    }
}

extern "C" void kernel_launch(void* const* d_in, const int* in_sizes, int n_in,
                              void* d_out, int out_size, void* d_ws, size_t ws_size,
                              hipStream_t stream) {
    const float* x   = (const float*)d_in[0];
    const float* w_g = (const float*)d_in[1];
    const float* b_g = (const float*)d_in[2];
    const float* w_t = (const float*)d_in[3];
    const float* b_t = (const float*)d_in[4];
    const float* w_p = (const float*)d_in[5];
    const float* b_p = (const float*)d_in[6];
    const float* w_o = (const float*)d_in[7];
    const float* b_o = (const float*)d_in[8];
    const float* gam = (const float*)d_in[9];
    const float* bet = (const float*)d_in[10];
    const float* mea = (const float*)d_in[11];
    const float* var = (const float*)d_in[12];
    float* out = (float*)d_out;

    unsigned short* qf = (unsigned short*)d_ws;
    unsigned short* kf = qf + QSZ;
    unsigned short* vt = kf + QSZ;
    float* s2b2 = (float*)(vt + QSZ);

    size_t base_b = 3 * QSZ * 2 + 2048;
    size_t per_b  = QSZ * 2 + (size_t)NB * NN * 8;
    int S = 1;
    if (base_b + 4 * per_b <= ws_size) S = 4;
    else if (base_b + 2 * per_b <= ws_size) S = 2;

    float2* pml = (float2*)((char*)d_ws + base_b);
    unsigned short* py = (unsigned short*)(pml + (size_t)S * NB * NN);

    prep_s2<<<1, 256, 0, stream>>>(w_o, b_o, gam, bet, mea, var, s2b2);
    prep_v<<<(int)(QSZ / 2048), 256, 0, stream>>>(x, w_g, b_g, vt);
    prep_qk<<<NB * 36 * 4, 256, 0, stream>>>(x, w_t, b_t, w_p, b_p, qf, kf);
    attn<<<NB * 36 * S, 256, 0, stream>>>(qf, kf, vt, py, pml, NN / S);
    combine<<<NB * 36, 256, 0, stream>>>(py, pml, x, s2b2, out, S);
}

// Round 16
// 139.756 us; speedup vs baseline: 2.8711x; 1.0120x over previous
//
#include <hip/hip_runtime.h>
#include <hip/hip_fp16.h>

#define NB 8
#define CC 256
#define NN 2304
#define TK 32
#define QSZ ((size_t)NB * NN * CC)

typedef __attribute__((ext_vector_type(8))) _Float16 half8;
typedef __attribute__((ext_vector_type(4))) float f32x4;
typedef __attribute__((ext_vector_type(4))) unsigned short us4;

#define MFMAH(a, b, c) __builtin_amdgcn_mfma_f32_16x16x32_f16((a), (b), (c), 0, 0, 0)

__device__ __forceinline__ unsigned short f2h(float f) {
    union { _Float16 x; unsigned short u; } c;
    c.x = (_Float16)f;
    return c.u;
}
__device__ __forceinline__ unsigned short f2bf(float f) {
    unsigned int u = __float_as_uint(f);
    u = (u + 0x7fffu + ((u >> 16) & 1u)) >> 16;
    return (unsigned short)u;
}
__device__ __forceinline__ float bf2f(unsigned short h) {
    return __uint_as_float(((unsigned int)h) << 16);
}

// ---- fold output projection + BN into per-channel scale/bias ----
__global__ void prep_s2(const float* __restrict__ w_o, const float* __restrict__ b_o,
                        const float* __restrict__ gam, const float* __restrict__ bet,
                        const float* __restrict__ mea, const float* __restrict__ var,
                        float* __restrict__ s2b2) {
    int c = threadIdx.x;
    float inv = gam[c] * rsqrtf(var[c] + 1e-5f);
    s2b2[c]      = w_o[c] * inv;
    s2b2[CC + c] = b_o[c] * inv + bet[c] - mea[c] * inv;
}

// ---- V^T projection: vt[b][c][m] = fp16(x * w_g + b_g) ----
__global__ __launch_bounds__(256) void prep_v(const float* __restrict__ x,
                                              const float* __restrict__ w_g,
                                              const float* __restrict__ b_g,
                                              unsigned short* __restrict__ vt) {
    size_t i = ((size_t)blockIdx.x * 256 + threadIdx.x) * 8;
    int c = (int)((i / NN) % CC);
    float wg = w_g[c], bg = b_g[c];
    float4 a = *(const float4*)&x[i];
    float4 d = *(const float4*)&x[i + 4];
    us4 o0, o1;
    o0[0] = f2h(a.x * wg + bg); o0[1] = f2h(a.y * wg + bg);
    o0[2] = f2h(a.z * wg + bg); o0[3] = f2h(a.w * wg + bg);
    o1[0] = f2h(d.x * wg + bg); o1[1] = f2h(d.y * wg + bg);
    o1[2] = f2h(d.z * wg + bg); o1[3] = f2h(d.w * wg + bg);
    *(us4*)&vt[i]     = o0;
    *(us4*)&vt[i + 4] = o1;
}

// ---- transpose + project x -> Q, K fp16, layout (B, N, C) ----
__global__ __launch_bounds__(256) void prep_qk(
    const float* __restrict__ x,
    const float* __restrict__ w_t, const float* __restrict__ b_t,
    const float* __restrict__ w_p, const float* __restrict__ b_p,
    unsigned short* __restrict__ qf, unsigned short* __restrict__ kf) {
    __shared__ float tile[64][65];
    int bid = blockIdx.x;
    int b  = bid / 144;
    int r  = bid % 144;
    int n0 = (r / 4) * 64;
    int c0 = (r % 4) * 64;
    int t  = threadIdx.x;
    int tx = t & 15, ty = t >> 4;

#pragma unroll
    for (int i = 0; i < 4; ++i) {
        int c = ty + i * 16;
        const float4 v = *(const float4*)&x[(size_t)(b * CC + c0 + c) * NN + n0 + tx * 4];
        tile[c][tx * 4 + 0] = v.x;
        tile[c][tx * 4 + 1] = v.y;
        tile[c][tx * 4 + 2] = v.z;
        tile[c][tx * 4 + 3] = v.w;
    }
    __syncthreads();
#pragma unroll
    for (int i = 0; i < 4; ++i) {
        int n = ty + i * 16;
        us4 qv, kv;
#pragma unroll
        for (int k = 0; k < 4; ++k) {
            int c = c0 + tx * 4 + k;
            float v = tile[tx * 4 + k][n];
            qv[k] = f2h(v * w_t[c] + b_t[c]);
            kv[k] = f2h(v * w_p[c] + b_p[c]);
        }
        size_t off = (size_t)(b * NN + n0 + n) * CC + c0 + tx * 4;
        *(us4*)&qf[off] = qv;
        *(us4*)&kf[off] = kv;
    }
}

// ---- flash attention: swapped QK^T with PERMUTED K staging so the S^T output
//      lands directly in the PV A-fragment layout (P fully in-register, no p_s) ----
__global__ __launch_bounds__(256, 2) void attn(
    const unsigned short* __restrict__ qf, const unsigned short* __restrict__ kf,
    const unsigned short* __restrict__ vt,
    unsigned short* __restrict__ py, float2* __restrict__ pml,
    int keys_per) {
    __shared__ __align__(16) unsigned short kh_s[TK][264];   // K fp16, padded, PERMUTED rows
    __shared__ __align__(16) unsigned short vt_s[CC][40];    // V^T fp16 (unpermuted)

    // XCD-chunked swizzle: blocks sharing (s,b) (same K/V) land on one XCD.
    int bid = (int)((blockIdx.x & 7) * (gridDim.x >> 3) + (blockIdx.x >> 3));
    int s  = bid / (NB * 36);
    int r  = bid % (NB * 36);
    int b  = r / 36;
    int n0 = (r % 36) * 64;
    int t  = threadIdx.x;
    int w  = t >> 6;
    int l  = t & 63;
    int g  = l >> 4;
    int ln = l & 15;
    int k0 = s * keys_per;

    // staging row permutation: LDS row r holds K key kperm(r);
    // kperm(r) = 8*((r&15)>>2) + 4*(r>>4) + (r&3)
    // => swapped-QK output s0[reg] = key 8g+reg, s1[reg] = key 8g+4+reg (q = ln)
    int srow  = t >> 3;                 // staging uses row = u>>5 below; perm computed per-u

    // Q fragments: lane holds Q[n0+16w+ln][kb*32 + g*8 + j] (B-operand after swap)
    half8 qh[8];
    {
        size_t base = (size_t)(b * NN + n0 + w * 16 + ln) * CC + g * 8;
#pragma unroll
        for (int kb = 0; kb < 8; ++kb)
            qh[kb] = *(const half8*)&qf[base + kb * 32];
    }
    (void)srow;

    f32x4 y[16];
#pragma unroll
    for (int ct = 0; ct < 16; ++ct) y[ct] = (f32x4){0.f, 0.f, 0.f, 0.f};
    float m_run = -1e30f;   // per-lane: q-row = ln
    float l_run = 0.f;

    // register staging (next tile)
    half8 skh[4], svv[4];

    // load + store tile 0 (K rows permuted at load)
#pragma unroll
    for (int i = 0; i < 4; ++i) {
        int u = i * 256 + t;
        int row = u >> 5, col = (u & 31) * 8;
        int kk = 8 * ((row & 15) >> 2) + 4 * (row >> 4) + (row & 3);
        skh[i] = *(const half8*)&kf[(size_t)(b * NN + k0 + kk) * CC + col];
        int c = u >> 2, mq = (u & 3) * 8;
        svv[i] = *(const half8*)&vt[(size_t)(b * CC + c) * NN + k0 + mq];
    }
#pragma unroll
    for (int i = 0; i < 4; ++i) {
        int u = i * 256 + t;
        int row = u >> 5, col = (u & 31) * 8;
        *(half8*)&kh_s[row][col] = skh[i];
        int c = u >> 2, mq = (u & 3) * 8;
        *(half8*)&vt_s[c][mq] = svv[i];
    }
    __syncthreads();

    int nkt = keys_per / TK;
    for (int kt = 0; kt < nkt; ++kt) {
        bool more = (kt + 1) < nkt;
        if (more) {   // issue next-tile loads; complete under compute (T14)
            int m1 = k0 + (kt + 1) * TK;
#pragma unroll
            for (int i = 0; i < 4; ++i) {
                int u = i * 256 + t;
                int row = u >> 5, col = (u & 31) * 8;
                int kk = 8 * ((row & 15) >> 2) + 4 * (row >> 4) + (row & 3);
                skh[i] = *(const half8*)&kf[(size_t)(b * NN + m1 + kk) * CC + col];
                int c = u >> 2, mq = (u & 3) * 8;
                svv[i] = *(const half8*)&vt[(size_t)(b * CC + c) * NN + m1 + mq];
            }
        }

        // S^T = K Q^T (swapped); permuted staging => s0[reg]=S[key 8g+reg][q=ln],
        // s1[reg]=S[key 8g+4+reg][q=ln]
        f32x4 sa0 = (f32x4){0.f,0.f,0.f,0.f}, sb0 = sa0, sa1 = sa0, sb1 = sa0;
        __builtin_amdgcn_s_setprio(1);
#pragma unroll
        for (int k2 = 0; k2 < 4; ++k2) {
            int kA = k2 * 2, kB = k2 * 2 + 1;
            half8 bA0 = *(const half8*)&kh_s[ln][kA * 32 + g * 8];
            half8 bA1 = *(const half8*)&kh_s[16 + ln][kA * 32 + g * 8];
            half8 bB0 = *(const half8*)&kh_s[ln][kB * 32 + g * 8];
            half8 bB1 = *(const half8*)&kh_s[16 + ln][kB * 32 + g * 8];
            sa0 = MFMAH(bA0, qh[kA], sa0);
            sa1 = MFMAH(bA1, qh[kA], sa1);
            sb0 = MFMAH(bB0, qh[kB], sb0);
            sb1 = MFMAH(bB1, qh[kB], sb1);
        }
        __builtin_amdgcn_s_setprio(0);
        f32x4 s0 = sa0 + sb0;
        f32x4 s1 = sa1 + sb1;

        // row-softmax: q=ln lane-local -> 7 local fmax + 2 shfl
        float vmax = fmaxf(fmaxf(fmaxf(s0[0], s0[1]), fmaxf(s0[2], s0[3])),
                           fmaxf(fmaxf(s1[0], s1[1]), fmaxf(s1[2], s1[3])));
        vmax = fmaxf(vmax, __shfl_xor(vmax, 16));
        vmax = fmaxf(vmax, __shfl_xor(vmax, 32));
        // defer-max (THR=8)
        if (__any(vmax > m_run + 8.f)) {
            float mnew  = fmaxf(m_run, vmax);
            float alpha = __expf(m_run - mnew);
            m_run = mnew;
            l_run *= alpha;
            float aj[4];
#pragma unroll
            for (int j = 0; j < 4; ++j) aj[j] = __shfl(alpha, g * 4 + j);
#pragma unroll
            for (int ct = 0; ct < 16; ++ct) {
                y[ct][0] *= aj[0]; y[ct][1] *= aj[1];
                y[ct][2] *= aj[2]; y[ct][3] *= aj[3];
            }
        }
        // P in-register: pa[j] = P[q=ln][key 8g+j] — exactly the PV A-fragment
        half8 pa;
        float psum = 0.f;
#pragma unroll
        for (int j = 0; j < 4; ++j) {
            float p0 = __expf(s0[j] - m_run);
            float p1 = __expf(s1[j] - m_run);
            pa[j]     = (_Float16)p0;
            pa[4 + j] = (_Float16)p1;
            psum += p0 + p1;
        }
        psum += __shfl_xor(psum, 16);
        psum += __shfl_xor(psum, 32);
        l_run += psum;

        // PV (A = in-register P; B = V^T from LDS, keys unpermuted = 8g+j ✓)
        __builtin_amdgcn_s_setprio(1);
#pragma unroll
        for (int ct = 0; ct < 16; ++ct) {
            half8 vb = *(const half8*)&vt_s[ct * 16 + ln][g * 8];
            y[ct] = MFMAH(pa, vb, y[ct]);
        }
        __builtin_amdgcn_s_setprio(0);

        if (more) {
            __syncthreads();   // all waves done reading current LDS tile
#pragma unroll
            for (int i = 0; i < 4; ++i) {
                int u = i * 256 + t;
                int row = u >> 5, col = (u & 31) * 8;
                *(half8*)&kh_s[row][col] = skh[i];
                int c = u >> 2, mq = (u & 3) * 8;
                *(half8*)&vt_s[c][mq] = svv[i];
            }
            __syncthreads();   // tile ready
        }
    }

    // write unnormalized partial y (bf16) + per-row (m, l); (m,l) lives at q=ln
#pragma unroll
    for (int j = 0; j < 4; ++j) {
        int n = n0 + w * 16 + g * 4 + j;
        size_t rowb = ((size_t)(s * NB + b) * NN + n) * CC;
#pragma unroll
        for (int ct = 0; ct < 16; ++ct)
            py[rowb + ct * 16 + ln] = f2bf(y[ct][j]);
    }
    if (g == 0)
        pml[(size_t)(s * NB + b) * NN + n0 + w * 16 + ln] = make_float2(m_run, l_run);
}

// ---- combine splits + out-proj/BN/residual; out layout (B,C,N) ----
__global__ __launch_bounds__(256) void combine(
    const unsigned short* __restrict__ py, const float2* __restrict__ pml,
    const float* __restrict__ x, const float* __restrict__ s2b2,
    float* __restrict__ out, int S) {
    __shared__ float ptile[64][65];
    int bid = blockIdx.x;
    int b  = bid / 36;
    int n0 = (bid % 36) * 64;
    int t  = threadIdx.x;
    int w  = t >> 6;
    int l  = t & 63;
    int n  = n0 + l;

    float M = -1e30f;
    for (int s = 0; s < S; ++s)
        M = fmaxf(M, pml[(size_t)(s * NB + b) * NN + n].x);
    float L = 0.f;
    for (int s = 0; s < S; ++s) {
        float2 ml = pml[(size_t)(s * NB + b) * NN + n];
        L += ml.y * __expf(ml.x - M);
    }

    float acc[64];
#pragma unroll
    for (int a = 0; a < 64; ++a) acc[a] = 0.f;

    for (int s = 0; s < S; ++s) {
        float wgt = __expf(pml[(size_t)(s * NB + b) * NN + n].x - M);
#pragma unroll
        for (int cc = 0; cc < 4; ++cc) {
            __syncthreads();
#pragma unroll
            for (int i = 0; i < 4; ++i) {
                int u = i * 256 + t;
                int row = u >> 4, c4 = (u & 15) * 4;
                us4 v = *(const us4*)&py[((size_t)(s * NB + b) * NN + n0 + row) * CC + cc * 64 + c4];
                ptile[row][c4 + 0] = bf2f(v[0]);
                ptile[row][c4 + 1] = bf2f(v[1]);
                ptile[row][c4 + 2] = bf2f(v[2]);
                ptile[row][c4 + 3] = bf2f(v[3]);
            }
            __syncthreads();
#pragma unroll
            for (int i = 0; i < 16; ++i)
                acc[cc * 16 + i] += wgt * ptile[l][w * 16 + i];
        }
    }

    float invL = 1.f / L;
#pragma unroll
    for (int cc = 0; cc < 4; ++cc) {
#pragma unroll
        for (int i = 0; i < 16; ++i) {
            int c = cc * 64 + w * 16 + i;
            size_t idx = ((size_t)b * CC + c) * NN + n;
            out[idx] = acc[cc * 16 + i] * invL * s2b2[c] + s2b2[CC + c] + x[idx];
        }
    }
}

extern "C" void kernel_launch(void* const* d_in, const int* in_sizes, int n_in,
                              void* d_out, int out_size, void* d_ws, size_t ws_size,
                              hipStream_t stream) {
    const float* x   = (const float*)d_in[0];
    const float* w_g = (const float*)d_in[1];
    const float* b_g = (const float*)d_in[2];
    const float* w_t = (const float*)d_in[3];
    const float* b_t = (const float*)d_in[4];
    const float* w_p = (const float*)d_in[5];
    const float* b_p = (const float*)d_in[6];
    const float* w_o = (const float*)d_in[7];
    const float* b_o = (const float*)d_in[8];
    const float* gam = (const float*)d_in[9];
    const float* bet = (const float*)d_in[10];
    const float* mea = (const float*)d_in[11];
    const float* var = (const float*)d_in[12];
    float* out = (float*)d_out;

    unsigned short* qf = (unsigned short*)d_ws;
    unsigned short* kf = qf + QSZ;
    unsigned short* vt = kf + QSZ;
    float* s2b2 = (float*)(vt + QSZ);

    size_t base_b = 3 * QSZ * 2 + 2048;
    size_t per_b  = QSZ * 2 + (size_t)NB * NN * 8;
    int S = 1;
    if (base_b + 4 * per_b <= ws_size) S = 4;
    else if (base_b + 2 * per_b <= ws_size) S = 2;

    float2* pml = (float2*)((char*)d_ws + base_b);
    unsigned short* py = (unsigned short*)(pml + (size_t)S * NB * NN);

    prep_s2<<<1, 256, 0, stream>>>(w_o, b_o, gam, bet, mea, var, s2b2);
    prep_v<<<(int)(QSZ / 2048), 256, 0, stream>>>(x, w_g, b_g, vt);
    prep_qk<<<NB * 36 * 4, 256, 0, stream>>>(x, w_t, b_t, w_p, b_p, qf, kf);
    attn<<<NB * 36 * S, 256, 0, stream>>>(qf, kf, vt, py, pml, NN / S);
    combine<<<NB * 36, 256, 0, stream>>>(py, pml, x, s2b2, out, S);
}